// Round 2
// baseline (347.518 us; speedup 1.0000x reference)
//
#include <hip/hip_runtime.h>
#include <stdint.h>

// Problem constants (AdaBIGGAN last adaptive-conv stage), all tensors float32.
#define B_  32
#define C_  96
#define HW_ 16384   // 128*128
#define IN_ 148

// ---------------------------------------------------------------------------
// Kernel 1: hypernetwork collapse.
//   scale[b,c] = y[b,:] . Wsum[c,:] + WbSum[c]
//   bias [b,c] = y[b,:] . Bg_w[c,:] + Bg_b[c]
// where Wsum[c,i] = sum_j Wg_w[(c*96+j)*148 + i], WbSum[c] = sum_j Wg_b[c*96+j].
// One block per c (96 blocks, 256 threads = 4 waves).
// ---------------------------------------------------------------------------
__global__ __launch_bounds__(256) void hyper_kernel(
    const float* __restrict__ Wg_w, const float* __restrict__ Wg_b,
    const float* __restrict__ Bg_w, const float* __restrict__ Bg_b,
    const float* __restrict__ y,
    float* __restrict__ scale, float* __restrict__ bias) {
    const int c   = blockIdx.x;
    const int tid = threadIdx.x;

    __shared__ float sW[IN_];   // column-sums of Wg_w rows for this c
    __shared__ float sB[IN_];   // Bg_w row for this c
    __shared__ float sWbS;      // sum of the Wg_b chunk

    if (tid < IN_) {
        float s = 0.f;
        const float* p = Wg_w + (size_t)c * C_ * IN_ + tid;
        #pragma unroll 4
        for (int j = 0; j < C_; ++j) s += p[(size_t)j * IN_];
        sW[tid] = s;
        sB[tid] = Bg_w[c * IN_ + tid];
    }
    if (tid < 64) {  // sum of 96 Wg_b entries, wave 0
        float v = Wg_b[c * C_ + tid];
        if (tid < C_ - 64) v += Wg_b[c * C_ + 64 + tid];
        #pragma unroll
        for (int off = 32; off > 0; off >>= 1) v += __shfl_down(v, off);
        if (tid == 0) sWbS = v;
    }
    __syncthreads();

    const int wave = tid >> 6, lane = tid & 63;
    for (int b = wave; b < B_; b += 4) {
        float y0 = y[b * IN_ + lane];
        float y1 = y[b * IN_ + 64 + lane];
        float ps = y0 * sW[lane] + y1 * sW[64 + lane];
        float pb = y0 * sB[lane] + y1 * sB[64 + lane];
        if (lane < IN_ - 128) {   // 148 = 64 + 64 + 20
            float y2 = y[b * IN_ + 128 + lane];
            ps += y2 * sW[128 + lane];
            pb += y2 * sB[128 + lane];
        }
        #pragma unroll
        for (int off = 32; off > 0; off >>= 1) {
            ps += __shfl_down(ps, off);
            pb += __shfl_down(pb, off);
        }
        if (lane == 0) {
            scale[b * C_ + c] = ps + sWbS;
            bias [b * C_ + c] = pb + Bg_b[c];
        }
    }
}

// ---------------------------------------------------------------------------
// Kernel 2: out = relu(h * scale[plane] + bias[plane]), float4 per thread.
// plane = b*C + c; HW/4 = 4096 vec4 per plane -> plane uniform per 256-block.
// ---------------------------------------------------------------------------
__global__ __launch_bounds__(256) void apply_kernel(
    const float* __restrict__ h, const float* __restrict__ scale,
    const float* __restrict__ bias, float* __restrict__ out) {
    const int idx   = blockIdx.x * 256 + threadIdx.x;  // vec4 index
    const int plane = idx >> 12;                        // / (HW/4)

    const float s  = scale[plane];
    const float bb = bias[plane];

    const float4 v = reinterpret_cast<const float4*>(h)[idx];
    float4 o;
    o.x = fmaxf(fmaf(v.x, s, bb), 0.f);
    o.y = fmaxf(fmaf(v.y, s, bb), 0.f);
    o.z = fmaxf(fmaf(v.z, s, bb), 0.f);
    o.w = fmaxf(fmaf(v.w, s, bb), 0.f);
    reinterpret_cast<float4*>(out)[idx] = o;
}

extern "C" void kernel_launch(void* const* d_in, const int* in_sizes, int n_in,
                              void* d_out, int out_size, void* d_ws, size_t ws_size,
                              hipStream_t stream) {
    const float* h    = (const float*)d_in[0];
    const float* y    = (const float*)d_in[1];
    const float* Wg_w = (const float*)d_in[2];
    const float* Wg_b = (const float*)d_in[3];
    const float* Bg_w = (const float*)d_in[4];
    const float* Bg_b = (const float*)d_in[5];
    float* out = (float*)d_out;

    // f32 scratch in d_ws: scale[B*C] then bias[B*C] (24 KB total).
    float* scale = (float*)d_ws;
    float* bias  = scale + B_ * C_;

    hyper_kernel<<<C_, 256, 0, stream>>>(Wg_w, Wg_b, Bg_w, Bg_b, y, scale, bias);

    const int nvec = (B_ * C_ * HW_) / 4;            // 12,582,912
    apply_kernel<<<nvec / 256, 256, 0, stream>>>(h, scale, bias, out);
}